// Round 5
// baseline (266.101 us; speedup 1.0000x reference)
//
#include <hip/hip_runtime.h>
#include <cstdint>
#include <cstddef>

// Problem dims (fixed by the reference): B=64, S=512, D=768, C=512
#define BB 64
#define SS 512
#define DD 768
#define CC 512

typedef __attribute__((ext_vector_type(8))) short short8;
typedef __attribute__((ext_vector_type(4))) float f32x4;

#define GLOBAL_AS __attribute__((address_space(1)))
#define LDS_AS __attribute__((address_space(3)))

// float -> bf16 bits, round-to-nearest-even
static __device__ __forceinline__ unsigned short f2bf(float f) {
  union { float f; unsigned u; } v; v.f = f;
  unsigned u = v.u;
  u += 0x7FFFu + ((u >> 16) & 1u);
  return (unsigned short)(u >> 16);
}

// async 16B/lane global->LDS copy (wave-uniform LDS base + lane*16)
static __device__ __forceinline__ void async_copy16(const void* g, void* l) {
  __builtin_amdgcn_global_load_lds((const GLOBAL_AS void*)g, (LDS_AS void*)l,
                                   16, 0, 0);
}

// ---------------------------------------------------------------------------
// Kernel 1: normalize label embeddings -> bf16 rows, XOR-swizzled.
// Row c element d stored at ((d>>3) ^ (c&7))*8 + (d&7): 16B chunk j -> slot
// j^(c&7). Global row stays contiguous (for global_load_lds); the MFMA-layout
// ds_read_b128 keeps a balanced bank distribution.
// ---------------------------------------------------------------------------
__global__ __launch_bounds__(256) void k_label_norm(const float* __restrict__ L,
                                                    unsigned short* __restrict__ Lnb) {
  const int c = blockIdx.x;
  const int tid = threadIdx.x;
  const float* row = L + (size_t)c * DD;
  float v[3];
  float s = 0.f;
#pragma unroll
  for (int k = 0; k < 3; k++) { v[k] = row[tid + 256 * k]; s += v[k] * v[k]; }
#pragma unroll
  for (int o = 32; o > 0; o >>= 1) s += __shfl_xor(s, o, 64);
  __shared__ float wsum[4];
  if ((tid & 63) == 0) wsum[tid >> 6] = s;
  __syncthreads();
  const float tot = wsum[0] + wsum[1] + wsum[2] + wsum[3];
  const float inv = 1.f / fmaxf(sqrtf(tot), 1e-8f);
  unsigned short* orow = Lnb + (size_t)c * DD;
  const int sw = c & 7;
#pragma unroll
  for (int k = 0; k < 3; k++) {
    const int d = tid + 256 * k;
    const int idx = (((d >> 3) ^ sw) << 3) | (d & 7);
    orow[idx] = f2bf(v[k] * inv);
  }
}

// ---------------------------------------------------------------------------
// Kernel 2: em[b,s] = exp(max_c cos(V[b,s],L[c]) - 1)   (sims <= 1 always, so
// softmax needs no separate max pass; the 1/sum lands in k_final).
// 512 blocks x 4 waves x 16 tokens (2 blocks/CU — round-2/3 A/B showed
// cross-block overlap of barrier drains is required). A-fragments in
// registers (96 VGPR, V read once). Ring-3 LDS staging, prefetch distance 2,
// hand-built barrier: s_waitcnt vmcnt(6) waits only for the chunk issued two
// iterations ago (already landed) — never vmcnt(0) like __syncthreads (the
// m97-plateau stall). Zero address VALU in the MFMA loop via factored XOR
// swizzle: off(kc) = mr*768 + (q^(mr&3))*8 + (kc^((mr>>2)&1))*32 [elems].
// ---------------------------------------------------------------------------
__global__ __launch_bounds__(256) void k_sims_max(const float* __restrict__ V,
                                                  const unsigned short* __restrict__ Lnb,
                                                  float* __restrict__ em_out) {
  const int tid = threadIdx.x;
  const int wave = tid >> 6;
  const int lane = tid & 63;
  const int q = lane >> 4;    // quad 0..3
  const int mr = lane & 15;   // row (token) for A, col (class) for B
  const int64_t tokBase = (int64_t)blockIdx.x * 64 + wave * 16;

  __shared__ unsigned short Bs[3][16 * DD];  // ring of 3 x 24576 B
  __shared__ float nrmS[4][16];              // wave-local (no barrier needed)

  // ---- stage chunk 0 into ring slot 0 (6 x 1KB copies per wave)
  {
    const char* src = (const char*)Lnb;
    char* dst = (char*)&Bs[0][0];
#pragma unroll
    for (int j = 0; j < 6; j++) {
      const int i = wave + 4 * j;
      async_copy16(src + i * 1024 + lane * 16, dst + i * 1024);
    }
  }

  // ---- load A fragments + squared norm (consumed here -> vmcnt drained)
  const float* arow = V + (tokBase + mr) * DD + q * 8;
  short8 afrag[24];
  float nrm2 = 0.f;
#pragma unroll
  for (int kc = 0; kc < 24; kc++) {
    const float4* p = (const float4*)(arow + kc * 32);
    const float4 x = p[0];
    const float4 y = p[1];
    short8 a;
    a[0] = (short)f2bf(x.x); a[1] = (short)f2bf(x.y);
    a[2] = (short)f2bf(x.z); a[3] = (short)f2bf(x.w);
    a[4] = (short)f2bf(y.x); a[5] = (short)f2bf(y.y);
    a[6] = (short)f2bf(y.z); a[7] = (short)f2bf(y.w);
    afrag[kc] = a;
    nrm2 += x.x * x.x + x.y * x.y + x.z * x.z + x.w * x.w;
    nrm2 += y.x * y.x + y.y * y.y + y.z * y.z + y.w * y.w;
  }
  nrm2 += __shfl_xor(nrm2, 16, 64);
  nrm2 += __shfl_xor(nrm2, 32, 64);
  if (q == 0) nrmS[wave][mr] = nrm2;

  // ---- stage chunk 1 into ring slot 1
  {
    const char* src = (const char*)(Lnb + (size_t)16 * DD);
    char* dst = (char*)&Bs[1][0];
#pragma unroll
    for (int j = 0; j < 6; j++) {
      const int i = wave + 4 * j;
      async_copy16(src + i * 1024 + lane * 16, dst + i * 1024);
    }
  }

  // lane-constant LDS read bases (zero VALU in the MFMA loop)
  const int swLo = mr & 3;
  const int swHi = (mr >> 2) & 1;
  const int elemBase = mr * DD + ((q ^ swLo) << 3);
  const int u0off = swHi ? 32 : 0;   // (0 ^ swHi) * 32
  const int u1off = swHi ? 0 : 32;   // (1 ^ swHi) * 32

  f32x4 vmax = {-3e38f, -3e38f, -3e38f, -3e38f};
  for (int cc = 0; cc < 32; cc++) {
    // wait for chunk cc (issued 2 iterations ago): 12 outstanding -> 6,
    // i.e. zero actual stall in steady state. Last iter: only 6 outstanding.
    if (cc != 31) {
      asm volatile("s_waitcnt vmcnt(6)" ::: "memory");
    } else {
      asm volatile("s_waitcnt vmcnt(0)" ::: "memory");
    }
    asm volatile("s_barrier" ::: "memory");  // all waves' chunk cc visible;
                                             // all waves done reading cc-1
    if (cc + 2 < 32) {
      const char* src = (const char*)(Lnb + (size_t)(cc + 2) * 16 * DD);
      char* dst = (char*)&Bs[(cc + 2) % 3][0];
#pragma unroll
      for (int j = 0; j < 6; j++) {
        const int i = wave + 4 * j;
        async_copy16(src + i * 1024 + lane * 16, dst + i * 1024);
      }
    }
    const unsigned short* b0 = &Bs[cc % 3][elemBase + u0off];
    const unsigned short* b1 = &Bs[cc % 3][elemBase + u1off];
    f32x4 acc = {0.f, 0.f, 0.f, 0.f};
#pragma unroll
    for (int t = 0; t < 12; t++) {
      const short8 bu0 = *(const short8*)(b0 + t * 64);
      acc = __builtin_amdgcn_mfma_f32_16x16x32_bf16(afrag[2 * t], bu0, acc, 0, 0, 0);
      const short8 bu1 = *(const short8*)(b1 + t * 64);
      acc = __builtin_amdgcn_mfma_f32_16x16x32_bf16(afrag[2 * t + 1], bu1, acc, 0, 0, 0);
    }
    vmax[0] = fmaxf(vmax[0], acc[0]);
    vmax[1] = fmaxf(vmax[1], acc[1]);
    vmax[2] = fmaxf(vmax[2], acc[2]);
    vmax[3] = fmaxf(vmax[3], acc[3]);
  }
  // reduce max over the 16 column-lanes of each quad
#pragma unroll
  for (int o = 1; o < 16; o <<= 1) {
#pragma unroll
    for (int r = 0; r < 4; r++) vmax[r] = fmaxf(vmax[r], __shfl_xor(vmax[r], o, 64));
  }
  // rows held by this quad are tokens q*4 + r; emit exp(m - 1)
  if (mr == 0) {
#pragma unroll
    for (int r = 0; r < 4; r++) {
      const float nr = nrmS[wave][q * 4 + r];
      const float m = vmax[r] / fmaxf(sqrtf(nr), 1e-8f);
      em_out[tokBase + q * 4 + r] = __expf(m - 1.f);
    }
  }
}

// ---------------------------------------------------------------------------
// Kernel 3: partial z weighted by exp(m-1) (softmax numerator; denominator
// applied in k_final). grid = B*nsc x 192 threads; second/last full V read.
// ---------------------------------------------------------------------------
__global__ __launch_bounds__(192) void k_zpart(const float* __restrict__ V,
                                               const float* __restrict__ em,
                                               float* __restrict__ zpart,
                                               int spc, int nsc) {
  const int blk = blockIdx.x;
  const int b = blk / nsc;
  const int sc = blk % nsc;
  const int tid = threadIdx.x;
  const float* vb = V + ((size_t)b * SS + (size_t)sc * spc) * DD + tid * 4;
  const float* bb = em + (size_t)b * SS + (size_t)sc * spc;
  float4 acc = {0.f, 0.f, 0.f, 0.f};
#pragma unroll 4
  for (int s = 0; s < spc; s++) {
    const float w = bb[s];
    const float4 x = *(const float4*)(vb + (size_t)s * DD);
    acc.x += w * x.x; acc.y += w * x.y; acc.z += w * x.z; acc.w += w * x.w;
  }
  *(float4*)(zpart + (size_t)blk * DD + tid * 4) = acc;
}

// ---------------------------------------------------------------------------
// Kernel 4: sum exp weights, reduce z-partials -> z (scaled), classifier.
// grid = 2*B blocks (b, class-half) x 256 threads; fc_w L2/L3-resident.
// ---------------------------------------------------------------------------
__global__ __launch_bounds__(256) void k_final(const float* __restrict__ zpart,
                                               const float* __restrict__ em,
                                               const float* __restrict__ fc_w,
                                               const float* __restrict__ fc_b,
                                               float* __restrict__ out,
                                               float* __restrict__ zout,
                                               int nsc) {
  const int b = blockIdx.x >> 1;
  const int half = blockIdx.x & 1;
  const int tid = threadIdx.x;
  // sum of exp weights for this batch
  const float* eb = em + (size_t)b * SS;
  float es = eb[tid] + eb[tid + 256];
#pragma unroll
  for (int o = 32; o > 0; o >>= 1) es += __shfl_xor(es, o, 64);
  __shared__ float wred[4];
  if ((tid & 63) == 0) wred[tid >> 6] = es;
  __shared__ float zs[DD];
  __syncthreads();
  const float inv = 1.f / (wred[0] + wred[1] + wred[2] + wred[3]);
  for (int i = tid; i < DD; i += 256) {
    float s = 0.f;
    for (int sc = 0; sc < nsc; sc++) s += zpart[((size_t)b * nsc + sc) * DD + i];
    s *= inv;
    zs[i] = s;
    if (half == 0) zout[(size_t)b * DD + i] = s;
  }
  __syncthreads();
  const int c = half * 256 + tid;
  const float4* w = (const float4*)(fc_w + (size_t)c * DD);
  float acc = 0.f;
  for (int d4 = 0; d4 < DD / 4; d4++) {
    const float4 ww = w[d4];
    acc += ww.x * zs[d4 * 4] + ww.y * zs[d4 * 4 + 1] +
           ww.z * zs[d4 * 4 + 2] + ww.w * zs[d4 * 4 + 3];
  }
  out[(size_t)b * CC + c] = acc + fc_b[c];
}

// ---------------------------------------------------------------------------
extern "C" void kernel_launch(void* const* d_in, const int* in_sizes, int n_in,
                              void* d_out, int out_size, void* d_ws, size_t ws_size,
                              hipStream_t stream) {
  const float* V  = (const float*)d_in[0];  // [64,512,768]
  const float* L  = (const float*)d_in[1];  // [512,768]
  const float* fw = (const float*)d_in[2];  // [512,768]
  const float* fb = (const float*)d_in[3];  // [512]
  float* out = (float*)d_out;               // [64*512] out, then [64*768] z

  char* ws = (char*)d_ws;
  unsigned short* Lnb = (unsigned short*)ws;            // 786432 B (swizzled)
  float* em    = (float*)(ws + 786432);                 // 131072 B  exp(m-1)
  float* zpart = (float*)(ws + 1048576);                // nsc*64*768*4 B

  // 16 s-chunks (4 MB total ws) if the workspace allows, else 8 (2.5 MB)
  const int nsc = (ws_size >= (size_t)1048576 + 16 * BB * DD * 4) ? 16 : 8;
  const int spc = SS / nsc;

  k_label_norm<<<CC, 256, 0, stream>>>(L, Lnb);
  k_sims_max<<<512, 256, 0, stream>>>(V, Lnb, em);
  k_zpart<<<BB * nsc, 192, 0, stream>>>(V, em, zpart, spc, nsc);
  k_final<<<2 * BB, 256, 0, stream>>>(zpart, em, fw, fb, out, out + BB * CC, nsc);
}

// Round 6
// 247.652 us; speedup vs baseline: 1.0745x; 1.0745x over previous
//
#include <hip/hip_runtime.h>
#include <cstdint>
#include <cstddef>

// Problem dims (fixed by the reference): B=64, S=512, D=768, C=512
#define BB 64
#define SS 512
#define DD 768
#define CC 512

typedef __attribute__((ext_vector_type(8))) short short8;
typedef __attribute__((ext_vector_type(4))) float f32x4;

#define GLOBAL_AS __attribute__((address_space(1)))
#define LDS_AS __attribute__((address_space(3)))

// float -> bf16 bits, round-to-nearest-even
static __device__ __forceinline__ unsigned short f2bf(float f) {
  union { float f; unsigned u; } v; v.f = f;
  unsigned u = v.u;
  u += 0x7FFFu + ((u >> 16) & 1u);
  return (unsigned short)(u >> 16);
}
// bf16 bits -> float
static __device__ __forceinline__ float bf2f(unsigned short u) {
  union { unsigned u; float f; } v; v.u = ((unsigned)u) << 16; return v.f;
}

// async 16B/lane global->LDS copy (wave-uniform LDS base + lane*16)
static __device__ __forceinline__ void async_copy16(const void* g, void* l) {
  __builtin_amdgcn_global_load_lds((const GLOBAL_AS void*)g, (LDS_AS void*)l,
                                   16, 0, 0);
}

// ---------------------------------------------------------------------------
// Kernel 1: normalize label embeddings -> bf16 rows, XOR-swizzled.
// Row c element d stored at ((d>>3) ^ (c&7))*8 + (d&7).
// ---------------------------------------------------------------------------
__global__ __launch_bounds__(256) void k_label_norm(const float* __restrict__ L,
                                                    unsigned short* __restrict__ Lnb) {
  const int c = blockIdx.x;
  const int tid = threadIdx.x;
  const float* row = L + (size_t)c * DD;
  float v[3];
  float s = 0.f;
#pragma unroll
  for (int k = 0; k < 3; k++) { v[k] = row[tid + 256 * k]; s += v[k] * v[k]; }
#pragma unroll
  for (int o = 32; o > 0; o >>= 1) s += __shfl_xor(s, o, 64);
  __shared__ float wsum[4];
  if ((tid & 63) == 0) wsum[tid >> 6] = s;
  __syncthreads();
  const float tot = wsum[0] + wsum[1] + wsum[2] + wsum[3];
  const float inv = 1.f / fmaxf(sqrtf(tot), 1e-8f);
  unsigned short* orow = Lnb + (size_t)c * DD;
  const int sw = c & 7;
#pragma unroll
  for (int k = 0; k < 3; k++) {
    const int d = tid + 256 * k;
    const int idx = (((d >> 3) ^ sw) << 3) | (d & 7);
    orow[idx] = f2bf(v[k] * inv);
  }
}

// ---------------------------------------------------------------------------
// Kernel 2 (big-ws path): V fp32 -> Vb bf16 + inv_norm. One wave per token.
// Pure BW: read 96 MB, write 48 MB. Removes all fp32->bf16 conversion (and
// its register pressure — the round-4 spill cause) from the MFMA kernel.
// ---------------------------------------------------------------------------
__global__ __launch_bounds__(256) void k_vprep(const float* __restrict__ V,
                                               unsigned short* __restrict__ Vb,
                                               float* __restrict__ inv_norm) {
  const int wave = threadIdx.x >> 6;
  const int lane = threadIdx.x & 63;
  const int tok = blockIdx.x * 4 + wave;
  const float* src = V + (size_t)tok * DD;
  unsigned short* dst = Vb + (size_t)tok * DD;
  float n2 = 0.f;
#pragma unroll
  for (int j = 0; j < 3; j++) {
    const int e = j * 256 + lane * 4;
    const float4 x = *(const float4*)(src + e);
    n2 += x.x * x.x + x.y * x.y + x.z * x.z + x.w * x.w;
    ushort4 o;
    o.x = f2bf(x.x); o.y = f2bf(x.y); o.z = f2bf(x.z); o.w = f2bf(x.w);
    *(ushort4*)(dst + e) = o;
  }
#pragma unroll
  for (int o = 32; o > 0; o >>= 1) n2 += __shfl_xor(n2, o, 64);
  if (lane == 0) inv_norm[tok] = 1.f / fmaxf(sqrtf(n2), 1e-8f);
}

// ---------------------------------------------------------------------------
// Kernel 3 (big-ws path): em[b,s] = exp(max_c cos(V[b,s],L[c]) - 1).
// 512 blocks x 2 waves x 32 tokens. Each wave holds TWO 16-token A-sets
// (192 VGPR) loaded DIRECTLY as short8 from Vb (no conversion temps -> no
// spill; __launch_bounds__(128,2) caps at 256). Every B ds_read_b128 feeds
// 2 MFMAs -> LDS read traffic (the binding pipe) halves vs 16 tok/wave.
// Proven round-2 structure: dbuf + __syncthreads (48 KB LDS -> 3 blocks/CU;
// ring-3/manual-vmcnt rejected by round 5). Zero address VALU via factored
// XOR swizzle: off(kc) = mr*768 + (q^(mr&3))*8 + (kc^((mr>>2)&1))*32 [elems].
// ---------------------------------------------------------------------------
__global__ __launch_bounds__(128, 2) void k_sims32(const unsigned short* __restrict__ Vb,
                                                   const float* __restrict__ inv_norm,
                                                   const unsigned short* __restrict__ Lnb,
                                                   float* __restrict__ em_out) {
  const int tid = threadIdx.x;
  const int wave = tid >> 6;
  const int lane = tid & 63;
  const int q = lane >> 4;    // quad 0..3
  const int mr = lane & 15;   // row (token) for A, col (class) for B
  const int64_t tokBase = (int64_t)blockIdx.x * 64 + wave * 32;

  __shared__ unsigned short Bs[2][16 * DD];  // 2 x 24576 B

  // ---- prefetch class-chunk 0 into buf 0 (12 x 1KB copies per wave)
  {
    const char* src = (const char*)Lnb;
    char* dst = (char*)&Bs[0][0];
#pragma unroll
    for (int j = 0; j < 12; j++) {
      const int i = wave + 2 * j;
      async_copy16(src + i * 1024 + lane * 16, dst + i * 1024);
    }
  }

  // ---- load A fragments straight into their registers (bf16, no temps)
  short8 afrag[2][24];
#pragma unroll
  for (int s = 0; s < 2; s++) {
    const short8* ap = (const short8*)(Vb + (tokBase + s * 16 + mr) * DD + q * 8);
#pragma unroll
    for (int kc = 0; kc < 24; kc++) afrag[s][kc] = ap[kc * 4];  // stride 32 elems
  }

  __syncthreads();  // buf0 staged (vmcnt drain)

  // lane-constant LDS read bases (zero VALU in the MFMA loop)
  const int swLo = mr & 3;
  const int swHi = (mr >> 2) & 1;
  const int elemBase = mr * DD + ((q ^ swLo) << 3);
  const int u0off = swHi ? 32 : 0;   // (0 ^ swHi) * 32
  const int u1off = swHi ? 0 : 32;   // (1 ^ swHi) * 32

  f32x4 vmax0 = {-3e38f, -3e38f, -3e38f, -3e38f};
  f32x4 vmax1 = {-3e38f, -3e38f, -3e38f, -3e38f};
  for (int cc = 0; cc < 32; cc++) {
    const int p = cc & 1;
    if (cc + 1 < 32) {
      const char* src = (const char*)(Lnb + (size_t)(cc + 1) * 16 * DD);
      char* dst = (char*)&Bs[p ^ 1][0];
#pragma unroll
      for (int j = 0; j < 12; j++) {
        const int i = wave + 2 * j;
        async_copy16(src + i * 1024 + lane * 16, dst + i * 1024);
      }
    }
    const unsigned short* b0 = &Bs[p][elemBase + u0off];
    const unsigned short* b1 = &Bs[p][elemBase + u1off];
    f32x4 a0 = {0.f, 0.f, 0.f, 0.f};
    f32x4 a1 = {0.f, 0.f, 0.f, 0.f};
#pragma unroll
    for (int t = 0; t < 12; t++) {
      const short8 bu0 = *(const short8*)(b0 + t * 64);
      a0 = __builtin_amdgcn_mfma_f32_16x16x32_bf16(afrag[0][2 * t], bu0, a0, 0, 0, 0);
      a1 = __builtin_amdgcn_mfma_f32_16x16x32_bf16(afrag[1][2 * t], bu0, a1, 0, 0, 0);
      const short8 bu1 = *(const short8*)(b1 + t * 64);
      a0 = __builtin_amdgcn_mfma_f32_16x16x32_bf16(afrag[0][2 * t + 1], bu1, a0, 0, 0, 0);
      a1 = __builtin_amdgcn_mfma_f32_16x16x32_bf16(afrag[1][2 * t + 1], bu1, a1, 0, 0, 0);
    }
    vmax0[0] = fmaxf(vmax0[0], a0[0]); vmax0[1] = fmaxf(vmax0[1], a0[1]);
    vmax0[2] = fmaxf(vmax0[2], a0[2]); vmax0[3] = fmaxf(vmax0[3], a0[3]);
    vmax1[0] = fmaxf(vmax1[0], a1[0]); vmax1[1] = fmaxf(vmax1[1], a1[1]);
    vmax1[2] = fmaxf(vmax1[2], a1[2]); vmax1[3] = fmaxf(vmax1[3], a1[3]);
    __syncthreads();  // drains prefetch vmcnt + guards buffer reuse
  }
  // reduce max over the 16 column-lanes of each quad
#pragma unroll
  for (int o = 1; o < 16; o <<= 1) {
#pragma unroll
    for (int r = 0; r < 4; r++) {
      vmax0[r] = fmaxf(vmax0[r], __shfl_xor(vmax0[r], o, 64));
      vmax1[r] = fmaxf(vmax1[r], __shfl_xor(vmax1[r], o, 64));
    }
  }
  if (mr == 0) {
#pragma unroll
    for (int r = 0; r < 4; r++) {
      const float i0 = inv_norm[tokBase + q * 4 + r];
      em_out[tokBase + q * 4 + r] = __expf(vmax0[r] * i0 - 1.f);
      const float i1 = inv_norm[tokBase + 16 + q * 4 + r];
      em_out[tokBase + 16 + q * 4 + r] = __expf(vmax1[r] * i1 - 1.f);
    }
  }
}

// ---------------------------------------------------------------------------
// Fallback sims kernel (small ws): round-2 proven structure, fp32 V loads,
// in-kernel norms, em output. 512 blocks x 256 threads.
// ---------------------------------------------------------------------------
__global__ __launch_bounds__(256) void k_sims16(const float* __restrict__ V,
                                                const unsigned short* __restrict__ Lnb,
                                                float* __restrict__ em_out) {
  const int tid = threadIdx.x;
  const int wave = tid >> 6;
  const int lane = tid & 63;
  const int q = lane >> 4;
  const int mr = lane & 15;
  const int64_t tokBase = (int64_t)blockIdx.x * 64 + wave * 16;

  __shared__ unsigned short Bs[2][16 * DD];
  __shared__ float nrmS[4][16];

  {
    const char* src = (const char*)Lnb;
    char* dst = (char*)&Bs[0][0];
#pragma unroll
    for (int j = 0; j < 6; j++) {
      const int i = wave + 4 * j;
      async_copy16(src + i * 1024 + lane * 16, dst + i * 1024);
    }
  }
  const float* arow = V + (tokBase + mr) * DD + q * 8;
  short8 afrag[24];
  float nrm2 = 0.f;
#pragma unroll
  for (int kc = 0; kc < 24; kc++) {
    const float4* p = (const float4*)(arow + kc * 32);
    const float4 x = p[0];
    const float4 y = p[1];
    short8 a;
    a[0] = (short)f2bf(x.x); a[1] = (short)f2bf(x.y);
    a[2] = (short)f2bf(x.z); a[3] = (short)f2bf(x.w);
    a[4] = (short)f2bf(y.x); a[5] = (short)f2bf(y.y);
    a[6] = (short)f2bf(y.z); a[7] = (short)f2bf(y.w);
    afrag[kc] = a;
    nrm2 += x.x * x.x + x.y * x.y + x.z * x.z + x.w * x.w;
    nrm2 += y.x * y.x + y.y * y.y + y.z * y.z + y.w * y.w;
  }
  nrm2 += __shfl_xor(nrm2, 16, 64);
  nrm2 += __shfl_xor(nrm2, 32, 64);
  if (q == 0) nrmS[wave][mr] = nrm2;
  __syncthreads();

  const int swLo = mr & 3;
  const int swHi = (mr >> 2) & 1;
  const int elemBase = mr * DD + ((q ^ swLo) << 3);
  const int u0off = swHi ? 32 : 0;
  const int u1off = swHi ? 0 : 32;

  f32x4 vmax = {-3e38f, -3e38f, -3e38f, -3e38f};
  for (int cc = 0; cc < 32; cc++) {
    const int p = cc & 1;
    if (cc + 1 < 32) {
      const char* src = (const char*)(Lnb + (size_t)(cc + 1) * 16 * DD);
      char* dst = (char*)&Bs[p ^ 1][0];
#pragma unroll
      for (int j = 0; j < 6; j++) {
        const int i = wave + 4 * j;
        async_copy16(src + i * 1024 + lane * 16, dst + i * 1024);
      }
    }
    const unsigned short* b0 = &Bs[p][elemBase + u0off];
    const unsigned short* b1 = &Bs[p][elemBase + u1off];
    f32x4 acc = {0.f, 0.f, 0.f, 0.f};
#pragma unroll
    for (int t = 0; t < 12; t++) {
      const short8 bu0 = *(const short8*)(b0 + t * 64);
      acc = __builtin_amdgcn_mfma_f32_16x16x32_bf16(afrag[2 * t], bu0, acc, 0, 0, 0);
      const short8 bu1 = *(const short8*)(b1 + t * 64);
      acc = __builtin_amdgcn_mfma_f32_16x16x32_bf16(afrag[2 * t + 1], bu1, acc, 0, 0, 0);
    }
    vmax[0] = fmaxf(vmax[0], acc[0]);
    vmax[1] = fmaxf(vmax[1], acc[1]);
    vmax[2] = fmaxf(vmax[2], acc[2]);
    vmax[3] = fmaxf(vmax[3], acc[3]);
    __syncthreads();
  }
#pragma unroll
  for (int o = 1; o < 16; o <<= 1) {
#pragma unroll
    for (int r = 0; r < 4; r++) vmax[r] = fmaxf(vmax[r], __shfl_xor(vmax[r], o, 64));
  }
  if (mr == 0) {
#pragma unroll
    for (int r = 0; r < 4; r++) {
      const float nr = nrmS[wave][q * 4 + r];
      const float m = vmax[r] / fmaxf(sqrtf(nr), 1e-8f);
      em_out[tokBase + q * 4 + r] = __expf(m - 1.f);
    }
  }
}

// ---------------------------------------------------------------------------
// Kernel 4 (big-ws): partial z from Vb (bf16), weighted by em. Thread owns
// 4 dims (ushort4 = 8 B/lane, coalesced). grid = B*nsc x 192.
// ---------------------------------------------------------------------------
__global__ __launch_bounds__(192) void k_zpart_bf(const unsigned short* __restrict__ Vb,
                                                  const float* __restrict__ em,
                                                  float* __restrict__ zpart,
                                                  int spc, int nsc) {
  const int blk = blockIdx.x;
  const int b = blk / nsc;
  const int sc = blk % nsc;
  const int tid = threadIdx.x;
  const unsigned short* vb = Vb + ((size_t)b * SS + (size_t)sc * spc) * DD + tid * 4;
  const float* bb = em + (size_t)b * SS + (size_t)sc * spc;
  float4 acc = {0.f, 0.f, 0.f, 0.f};
#pragma unroll 4
  for (int s = 0; s < spc; s++) {
    const float w = bb[s];
    const ushort4 u = *(const ushort4*)(vb + (size_t)s * DD);
    acc.x += w * bf2f(u.x); acc.y += w * bf2f(u.y);
    acc.z += w * bf2f(u.z); acc.w += w * bf2f(u.w);
  }
  *(float4*)(zpart + (size_t)blk * DD + tid * 4) = acc;
}

// Fallback zpart: fp32 V.
__global__ __launch_bounds__(192) void k_zpart_f32(const float* __restrict__ V,
                                                   const float* __restrict__ em,
                                                   float* __restrict__ zpart,
                                                   int spc, int nsc) {
  const int blk = blockIdx.x;
  const int b = blk / nsc;
  const int sc = blk % nsc;
  const int tid = threadIdx.x;
  const float* vb = V + ((size_t)b * SS + (size_t)sc * spc) * DD + tid * 4;
  const float* bb = em + (size_t)b * SS + (size_t)sc * spc;
  float4 acc = {0.f, 0.f, 0.f, 0.f};
#pragma unroll 4
  for (int s = 0; s < spc; s++) {
    const float w = bb[s];
    const float4 x = *(const float4*)(vb + (size_t)s * DD);
    acc.x += w * x.x; acc.y += w * x.y; acc.z += w * x.z; acc.w += w * x.w;
  }
  *(float4*)(zpart + (size_t)blk * DD + tid * 4) = acc;
}

// ---------------------------------------------------------------------------
// Kernel 5: sum em, reduce z-partials -> z (scaled), classifier.
// grid = 2*B blocks (b, class-half) x 256 threads.
// ---------------------------------------------------------------------------
__global__ __launch_bounds__(256) void k_final(const float* __restrict__ zpart,
                                               const float* __restrict__ em,
                                               const float* __restrict__ fc_w,
                                               const float* __restrict__ fc_b,
                                               float* __restrict__ out,
                                               float* __restrict__ zout,
                                               int nsc) {
  const int b = blockIdx.x >> 1;
  const int half = blockIdx.x & 1;
  const int tid = threadIdx.x;
  const float* eb = em + (size_t)b * SS;
  float es = eb[tid] + eb[tid + 256];
#pragma unroll
  for (int o = 32; o > 0; o >>= 1) es += __shfl_xor(es, o, 64);
  __shared__ float wred[4];
  if ((tid & 63) == 0) wred[tid >> 6] = es;
  __shared__ float zs[DD];
  __syncthreads();
  const float inv = 1.f / (wred[0] + wred[1] + wred[2] + wred[3]);
  for (int i = tid; i < DD; i += 256) {
    float s = 0.f;
    for (int sc = 0; sc < nsc; sc++) s += zpart[((size_t)b * nsc + sc) * DD + i];
    s *= inv;
    zs[i] = s;
    if (half == 0) zout[(size_t)b * DD + i] = s;
  }
  __syncthreads();
  const int c = half * 256 + tid;
  const float4* w = (const float4*)(fc_w + (size_t)c * DD);
  float acc = 0.f;
  for (int d4 = 0; d4 < DD / 4; d4++) {
    const float4 ww = w[d4];
    acc += ww.x * zs[d4 * 4] + ww.y * zs[d4 * 4 + 1] +
           ww.z * zs[d4 * 4 + 2] + ww.w * zs[d4 * 4 + 3];
  }
  out[(size_t)b * CC + c] = acc + fc_b[c];
}

// ---------------------------------------------------------------------------
extern "C" void kernel_launch(void* const* d_in, const int* in_sizes, int n_in,
                              void* d_out, int out_size, void* d_ws, size_t ws_size,
                              hipStream_t stream) {
  const float* V  = (const float*)d_in[0];  // [64,512,768]
  const float* L  = (const float*)d_in[1];  // [512,768]
  const float* fw = (const float*)d_in[2];  // [512,768]
  const float* fb = (const float*)d_in[3];  // [512]
  float* out = (float*)d_out;               // [64*512] out, then [64*768] z

  char* ws = (char*)d_ws;
  unsigned short* Lnb = (unsigned short*)ws;            // [0, 768K)
  float* em       = (float*)(ws + 786432);              // [768K, 896K)
  float* inv_norm = (float*)(ws + 917504);              // [896K, 1M)
  unsigned short* Vb = (unsigned short*)(ws + 1048576); // [1M, 1M+48M)
  const size_t vb_bytes = (size_t)BB * SS * DD * 2;     // 48 MB

  const size_t need16 = 1048576 + vb_bytes + (size_t)16 * BB * DD * 4;
  const bool big = ws_size >= need16;

  k_label_norm<<<CC, 256, 0, stream>>>(L, Lnb);
  if (big) {
    const int nsc = 16, spc = SS / nsc;
    float* zpart = (float*)(ws + 1048576 + vb_bytes);
    k_vprep<<<BB * SS / 4, 256, 0, stream>>>(V, Vb, inv_norm);
    k_sims32<<<512, 128, 0, stream>>>(Vb, inv_norm, Lnb, em);
    k_zpart_bf<<<BB * nsc, 192, 0, stream>>>(Vb, em, zpart, spc, nsc);
    k_final<<<2 * BB, 256, 0, stream>>>(zpart, em, fw, fb, out, out + BB * CC, nsc);
  } else {
    const int nsc = 8, spc = SS / nsc;
    float* zpart = (float*)(ws + 1048576);
    k_sims16<<<512, 256, 0, stream>>>(V, Lnb, em);
    k_zpart_f32<<<BB * nsc, 192, 0, stream>>>(V, em, zpart, spc, nsc);
    k_final<<<2 * BB, 256, 0, stream>>>(zpart, em, fw, fb, out, out + BB * CC, nsc);
  }
}

// Round 7
// 244.008 us; speedup vs baseline: 1.0905x; 1.0149x over previous
//
#include <hip/hip_runtime.h>
#include <cstdint>
#include <cstddef>

// Problem dims (fixed by the reference): B=64, S=512, D=768, C=512
#define BB 64
#define SS 512
#define DD 768
#define CC 512

typedef __attribute__((ext_vector_type(8))) short short8;
typedef __attribute__((ext_vector_type(4))) float f32x4;
typedef __attribute__((ext_vector_type(4))) unsigned short u16x4;

#define GLOBAL_AS __attribute__((address_space(1)))
#define LDS_AS __attribute__((address_space(3)))

// float -> bf16 bits, round-to-nearest-even
static __device__ __forceinline__ unsigned short f2bf(float f) {
  union { float f; unsigned u; } v; v.f = f;
  unsigned u = v.u;
  u += 0x7FFFu + ((u >> 16) & 1u);
  return (unsigned short)(u >> 16);
}
// bf16 bits -> float
static __device__ __forceinline__ float bf2f(unsigned short u) {
  union { unsigned u; float f; } v; v.u = ((unsigned)u) << 16; return v.f;
}

// async 16B/lane global->LDS copy (wave-uniform LDS base + lane*16)
static __device__ __forceinline__ void async_copy16(const void* g, void* l) {
  __builtin_amdgcn_global_load_lds((const GLOBAL_AS void*)g, (LDS_AS void*)l,
                                   16, 0, 0);
}

// ---------------------------------------------------------------------------
// Kernel 1: normalize label embeddings -> bf16 rows, XOR-swizzled.
// Row c element d stored at ((d>>3) ^ (c&7))*8 + (d&7).
// ---------------------------------------------------------------------------
__global__ __launch_bounds__(256) void k_label_norm(const float* __restrict__ L,
                                                    unsigned short* __restrict__ Lnb) {
  const int c = blockIdx.x;
  const int tid = threadIdx.x;
  const float* row = L + (size_t)c * DD;
  float v[3];
  float s = 0.f;
#pragma unroll
  for (int k = 0; k < 3; k++) { v[k] = row[tid + 256 * k]; s += v[k] * v[k]; }
#pragma unroll
  for (int o = 32; o > 0; o >>= 1) s += __shfl_xor(s, o, 64);
  __shared__ float wsum[4];
  if ((tid & 63) == 0) wsum[tid >> 6] = s;
  __syncthreads();
  const float tot = wsum[0] + wsum[1] + wsum[2] + wsum[3];
  const float inv = 1.f / fmaxf(sqrtf(tot), 1e-8f);
  unsigned short* orow = Lnb + (size_t)c * DD;
  const int sw = c & 7;
#pragma unroll
  for (int k = 0; k < 3; k++) {
    const int d = tid + 256 * k;
    const int idx = (((d >> 3) ^ sw) << 3) | (d & 7);
    orow[idx] = f2bf(v[k] * inv);
  }
}

// ---------------------------------------------------------------------------
// Kernel 2: V fp32 -> Vb bf16 + inv_norm. One wave per token. Pure BW.
// Nontemporal: V is read-once, Vb won't fit L2 anyway — avoid RFO/pollution.
// ---------------------------------------------------------------------------
__global__ __launch_bounds__(256) void k_vprep(const float* __restrict__ V,
                                               unsigned short* __restrict__ Vb,
                                               float* __restrict__ inv_norm) {
  const int wave = threadIdx.x >> 6;
  const int lane = threadIdx.x & 63;
  const int tok = blockIdx.x * 4 + wave;
  const float* src = V + (size_t)tok * DD;
  unsigned short* dst = Vb + (size_t)tok * DD;
  float n2 = 0.f;
#pragma unroll
  for (int j = 0; j < 3; j++) {
    const int e = j * 256 + lane * 4;
    const f32x4 x = __builtin_nontemporal_load((const f32x4*)(src + e));
    n2 += x[0] * x[0] + x[1] * x[1] + x[2] * x[2] + x[3] * x[3];
    u16x4 o;
    o[0] = f2bf(x[0]); o[1] = f2bf(x[1]); o[2] = f2bf(x[2]); o[3] = f2bf(x[3]);
    __builtin_nontemporal_store(o, (u16x4*)(dst + e));
  }
#pragma unroll
  for (int o = 32; o > 0; o >>= 1) n2 += __shfl_xor(n2, o, 64);
  if (lane == 0) inv_norm[tok] = 1.f / fmaxf(sqrtf(n2), 1e-8f);
}

// ---------------------------------------------------------------------------
// Kernel 3: em[b,s] = exp(max_c cos(V[b,s],L[c]) - 1).  CLASS-SPLIT layout:
// 256 blocks x 8 waves (512 thr -> guaranteed 2 waves/SIMD). Waves 0-3 own
// classes 0-255, waves 4-7 own classes 256-511; wave (h, wq) covers tokens
// [wq*32, wq*32+32) of the block's 128. Per iteration the block stages one
// 16-class chunk per half (2 x 24 KB, dbuf = 96 KB LDS): vs round 6 this
// halves staging L2 traffic (200 MB), halves barrier count (16), and doubles
// waves/SIMD — LDS read traffic unchanged (2 MFMAs per ds_read_b128 via two
// 16-token A-sets = 192 VGPR, loaded directly as bf16 from Vb; no conversion
// temps, the round-4 spill cause). Zero address VALU via the factored XOR
// swizzle: off(kc) = mr*768 + (q^(mr&3))*8 + (kc^((mr>>2)&1))*32 [elems].
// Halves' maxima combined through LDS before the exp.
// ---------------------------------------------------------------------------
__global__ __launch_bounds__(512, 2) void k_sims_hs(const unsigned short* __restrict__ Vb,
                                                    const float* __restrict__ inv_norm,
                                                    const unsigned short* __restrict__ Lnb,
                                                    float* __restrict__ em_out) {
  const int tid = threadIdx.x;
  const int wave = tid >> 6;
  const int lane = tid & 63;
  const int q = lane >> 4;    // quad 0..3
  const int mr = lane & 15;   // row (token) for A, col (class) for B
  const int h = wave >> 2;    // class half (0: c<256, 1: c>=256)
  const int wq = wave & 3;    // token group within block
  const int64_t tokBase = (int64_t)blockIdx.x * 128 + wq * 32;

  __shared__ unsigned short Bs[2][2][16 * DD];  // [dbuf][half][16x768] = 96 KB
  __shared__ float mS[2][128];                  // per-half token maxima

  // ---- stage chunk 0 of own half into buf 0 (6 x 1KB copies per wave)
  {
    const char* src = (const char*)(Lnb + (size_t)(h * 16) * 16 * DD);
    char* dst = (char*)&Bs[0][h][0];
#pragma unroll
    for (int j = 0; j < 6; j++) {
      const int i = wq * 6 + j;
      async_copy16(src + i * 1024 + lane * 16, dst + i * 1024);
    }
  }

  // ---- load A fragments straight into their registers (bf16, no temps)
  short8 afrag[2][24];
#pragma unroll
  for (int s = 0; s < 2; s++) {
    const short8* ap = (const short8*)(Vb + (tokBase + s * 16 + mr) * DD + q * 8);
#pragma unroll
    for (int kc = 0; kc < 24; kc++) afrag[s][kc] = ap[kc * 4];  // stride 32 elems
  }

  __syncthreads();  // buf0 staged (vmcnt drain)

  // lane-constant LDS read bases (zero VALU in the MFMA loop)
  const int swLo = mr & 3;
  const int swHi = (mr >> 2) & 1;
  const int elemBase = mr * DD + ((q ^ swLo) << 3);
  const int u0off = swHi ? 32 : 0;   // (0 ^ swHi) * 32
  const int u1off = swHi ? 0 : 32;   // (1 ^ swHi) * 32

  f32x4 vmax0 = {-3e38f, -3e38f, -3e38f, -3e38f};
  f32x4 vmax1 = {-3e38f, -3e38f, -3e38f, -3e38f};
  for (int cc = 0; cc < 16; cc++) {
    const int p = cc & 1;
    if (cc + 1 < 16) {
      const char* src = (const char*)(Lnb + (size_t)(h * 16 + cc + 1) * 16 * DD);
      char* dst = (char*)&Bs[p ^ 1][h][0];
#pragma unroll
      for (int j = 0; j < 6; j++) {
        const int i = wq * 6 + j;
        async_copy16(src + i * 1024 + lane * 16, dst + i * 1024);
      }
    }
    const unsigned short* b0 = &Bs[p][h][elemBase + u0off];
    const unsigned short* b1 = &Bs[p][h][elemBase + u1off];
    f32x4 a0 = {0.f, 0.f, 0.f, 0.f};
    f32x4 a1 = {0.f, 0.f, 0.f, 0.f};
#pragma unroll
    for (int t = 0; t < 12; t++) {
      const short8 bu0 = *(const short8*)(b0 + t * 64);
      a0 = __builtin_amdgcn_mfma_f32_16x16x32_bf16(afrag[0][2 * t], bu0, a0, 0, 0, 0);
      a1 = __builtin_amdgcn_mfma_f32_16x16x32_bf16(afrag[1][2 * t], bu0, a1, 0, 0, 0);
      const short8 bu1 = *(const short8*)(b1 + t * 64);
      a0 = __builtin_amdgcn_mfma_f32_16x16x32_bf16(afrag[0][2 * t + 1], bu1, a0, 0, 0, 0);
      a1 = __builtin_amdgcn_mfma_f32_16x16x32_bf16(afrag[1][2 * t + 1], bu1, a1, 0, 0, 0);
    }
    vmax0[0] = fmaxf(vmax0[0], a0[0]); vmax0[1] = fmaxf(vmax0[1], a0[1]);
    vmax0[2] = fmaxf(vmax0[2], a0[2]); vmax0[3] = fmaxf(vmax0[3], a0[3]);
    vmax1[0] = fmaxf(vmax1[0], a1[0]); vmax1[1] = fmaxf(vmax1[1], a1[1]);
    vmax1[2] = fmaxf(vmax1[2], a1[2]); vmax1[3] = fmaxf(vmax1[3], a1[3]);
    __syncthreads();  // drains prefetch vmcnt + guards buffer reuse
  }
  // reduce max over the 16 column-lanes (classes) of each quad
#pragma unroll
  for (int o = 1; o < 16; o <<= 1) {
#pragma unroll
    for (int r = 0; r < 4; r++) {
      vmax0[r] = fmaxf(vmax0[r], __shfl_xor(vmax0[r], o, 64));
      vmax1[r] = fmaxf(vmax1[r], __shfl_xor(vmax1[r], o, 64));
    }
  }
  // publish per-half maxima (token rows are q*4 + r per 16-token set)
  if (mr == 0) {
#pragma unroll
    for (int r = 0; r < 4; r++) {
      mS[h][wq * 32 + q * 4 + r] = vmax0[r];
      mS[h][wq * 32 + 16 + q * 4 + r] = vmax1[r];
    }
  }
  __syncthreads();
  // half-0 waves combine both halves and emit em = exp(m - 1)
  if (h == 0 && mr == 0) {
#pragma unroll
    for (int s = 0; s < 2; s++) {
#pragma unroll
      for (int r = 0; r < 4; r++) {
        const int tl = wq * 32 + s * 16 + q * 4 + r;
        const int64_t gt = (int64_t)blockIdx.x * 128 + tl;
        const float m = fmaxf(mS[0][tl], mS[1][tl]) * inv_norm[gt];
        em_out[gt] = __expf(m - 1.f);
      }
    }
  }
}

// ---------------------------------------------------------------------------
// Fallback sims kernel (small ws): round-2 proven structure, fp32 V loads.
// ---------------------------------------------------------------------------
__global__ __launch_bounds__(256) void k_sims16(const float* __restrict__ V,
                                                const unsigned short* __restrict__ Lnb,
                                                float* __restrict__ em_out) {
  const int tid = threadIdx.x;
  const int wave = tid >> 6;
  const int lane = tid & 63;
  const int q = lane >> 4;
  const int mr = lane & 15;
  const int64_t tokBase = (int64_t)blockIdx.x * 64 + wave * 16;

  __shared__ unsigned short Bs[2][16 * DD];
  __shared__ float nrmS[4][16];

  {
    const char* src = (const char*)Lnb;
    char* dst = (char*)&Bs[0][0];
#pragma unroll
    for (int j = 0; j < 6; j++) {
      const int i = wave + 4 * j;
      async_copy16(src + i * 1024 + lane * 16, dst + i * 1024);
    }
  }
  const float* arow = V + (tokBase + mr) * DD + q * 8;
  short8 afrag[24];
  float nrm2 = 0.f;
#pragma unroll
  for (int kc = 0; kc < 24; kc++) {
    const float4* p = (const float4*)(arow + kc * 32);
    const float4 x = p[0];
    const float4 y = p[1];
    short8 a;
    a[0] = (short)f2bf(x.x); a[1] = (short)f2bf(x.y);
    a[2] = (short)f2bf(x.z); a[3] = (short)f2bf(x.w);
    a[4] = (short)f2bf(y.x); a[5] = (short)f2bf(y.y);
    a[6] = (short)f2bf(y.z); a[7] = (short)f2bf(y.w);
    afrag[kc] = a;
    nrm2 += x.x * x.x + x.y * x.y + x.z * x.z + x.w * x.w;
    nrm2 += y.x * y.x + y.y * y.y + y.z * y.z + y.w * y.w;
  }
  nrm2 += __shfl_xor(nrm2, 16, 64);
  nrm2 += __shfl_xor(nrm2, 32, 64);
  if (q == 0) nrmS[wave][mr] = nrm2;
  __syncthreads();

  const int swLo = mr & 3;
  const int swHi = (mr >> 2) & 1;
  const int elemBase = mr * DD + ((q ^ swLo) << 3);
  const int u0off = swHi ? 32 : 0;
  const int u1off = swHi ? 0 : 32;

  f32x4 vmax = {-3e38f, -3e38f, -3e38f, -3e38f};
  for (int cc = 0; cc < 32; cc++) {
    const int p = cc & 1;
    if (cc + 1 < 32) {
      const char* src = (const char*)(Lnb + (size_t)(cc + 1) * 16 * DD);
      char* dst = (char*)&Bs[p ^ 1][0];
#pragma unroll
      for (int j = 0; j < 6; j++) {
        const int i = wave + 4 * j;
        async_copy16(src + i * 1024 + lane * 16, dst + i * 1024);
      }
    }
    const unsigned short* b0 = &Bs[p][elemBase + u0off];
    const unsigned short* b1 = &Bs[p][elemBase + u1off];
    f32x4 acc = {0.f, 0.f, 0.f, 0.f};
#pragma unroll
    for (int t = 0; t < 12; t++) {
      const short8 bu0 = *(const short8*)(b0 + t * 64);
      acc = __builtin_amdgcn_mfma_f32_16x16x32_bf16(afrag[2 * t], bu0, acc, 0, 0, 0);
      const short8 bu1 = *(const short8*)(b1 + t * 64);
      acc = __builtin_amdgcn_mfma_f32_16x16x32_bf16(afrag[2 * t + 1], bu1, acc, 0, 0, 0);
    }
    vmax[0] = fmaxf(vmax[0], acc[0]);
    vmax[1] = fmaxf(vmax[1], acc[1]);
    vmax[2] = fmaxf(vmax[2], acc[2]);
    vmax[3] = fmaxf(vmax[3], acc[3]);
    __syncthreads();
  }
#pragma unroll
  for (int o = 1; o < 16; o <<= 1) {
#pragma unroll
    for (int r = 0; r < 4; r++) vmax[r] = fmaxf(vmax[r], __shfl_xor(vmax[r], o, 64));
  }
  if (mr == 0) {
#pragma unroll
    for (int r = 0; r < 4; r++) {
      const float nr = nrmS[wave][q * 4 + r];
      const float m = vmax[r] / fmaxf(sqrtf(nr), 1e-8f);
      em_out[tokBase + q * 4 + r] = __expf(m - 1.f);
    }
  }
}

// ---------------------------------------------------------------------------
// Kernel 4 (big-ws): partial z from Vb (bf16), weighted by em.
// ---------------------------------------------------------------------------
__global__ __launch_bounds__(192) void k_zpart_bf(const unsigned short* __restrict__ Vb,
                                                  const float* __restrict__ em,
                                                  float* __restrict__ zpart,
                                                  int spc, int nsc) {
  const int blk = blockIdx.x;
  const int b = blk / nsc;
  const int sc = blk % nsc;
  const int tid = threadIdx.x;
  const unsigned short* vb = Vb + ((size_t)b * SS + (size_t)sc * spc) * DD + tid * 4;
  const float* bb = em + (size_t)b * SS + (size_t)sc * spc;
  float4 acc = {0.f, 0.f, 0.f, 0.f};
#pragma unroll 4
  for (int s = 0; s < spc; s++) {
    const float w = bb[s];
    const ushort4 u = *(const ushort4*)(vb + (size_t)s * DD);
    acc.x += w * bf2f(u.x); acc.y += w * bf2f(u.y);
    acc.z += w * bf2f(u.z); acc.w += w * bf2f(u.w);
  }
  *(float4*)(zpart + (size_t)blk * DD + tid * 4) = acc;
}

// Fallback zpart: fp32 V.
__global__ __launch_bounds__(192) void k_zpart_f32(const float* __restrict__ V,
                                                   const float* __restrict__ em,
                                                   float* __restrict__ zpart,
                                                   int spc, int nsc) {
  const int blk = blockIdx.x;
  const int b = blk / nsc;
  const int sc = blk % nsc;
  const int tid = threadIdx.x;
  const float* vb = V + ((size_t)b * SS + (size_t)sc * spc) * DD + tid * 4;
  const float* bb = em + (size_t)b * SS + (size_t)sc * spc;
  float4 acc = {0.f, 0.f, 0.f, 0.f};
#pragma unroll 4
  for (int s = 0; s < spc; s++) {
    const float w = bb[s];
    const float4 x = *(const float4*)(vb + (size_t)s * DD);
    acc.x += w * x.x; acc.y += w * x.y; acc.z += w * x.z; acc.w += w * x.w;
  }
  *(float4*)(zpart + (size_t)blk * DD + tid * 4) = acc;
}

// ---------------------------------------------------------------------------
// Kernel 5: sum em, reduce z-partials -> z (scaled), classifier.
// ---------------------------------------------------------------------------
__global__ __launch_bounds__(256) void k_final(const float* __restrict__ zpart,
                                               const float* __restrict__ em,
                                               const float* __restrict__ fc_w,
                                               const float* __restrict__ fc_b,
                                               float* __restrict__ out,
                                               float* __restrict__ zout,
                                               int nsc) {
  const int b = blockIdx.x >> 1;
  const int half = blockIdx.x & 1;
  const int tid = threadIdx.x;
  const float* eb = em + (size_t)b * SS;
  float es = eb[tid] + eb[tid + 256];
#pragma unroll
  for (int o = 32; o > 0; o >>= 1) es += __shfl_xor(es, o, 64);
  __shared__ float wred[4];
  if ((tid & 63) == 0) wred[tid >> 6] = es;
  __shared__ float zs[DD];
  __syncthreads();
  const float inv = 1.f / (wred[0] + wred[1] + wred[2] + wred[3]);
  for (int i = tid; i < DD; i += 256) {
    float s = 0.f;
    for (int sc = 0; sc < nsc; sc++) s += zpart[((size_t)b * nsc + sc) * DD + i];
    s *= inv;
    zs[i] = s;
    if (half == 0) zout[(size_t)b * DD + i] = s;
  }
  __syncthreads();
  const int c = half * 256 + tid;
  const float4* w = (const float4*)(fc_w + (size_t)c * DD);
  float acc = 0.f;
  for (int d4 = 0; d4 < DD / 4; d4++) {
    const float4 ww = w[d4];
    acc += ww.x * zs[d4 * 4] + ww.y * zs[d4 * 4 + 1] +
           ww.z * zs[d4 * 4 + 2] + ww.w * zs[d4 * 4 + 3];
  }
  out[(size_t)b * CC + c] = acc + fc_b[c];
}

// ---------------------------------------------------------------------------
extern "C" void kernel_launch(void* const* d_in, const int* in_sizes, int n_in,
                              void* d_out, int out_size, void* d_ws, size_t ws_size,
                              hipStream_t stream) {
  const float* V  = (const float*)d_in[0];  // [64,512,768]
  const float* L  = (const float*)d_in[1];  // [512,768]
  const float* fw = (const float*)d_in[2];  // [512,768]
  const float* fb = (const float*)d_in[3];  // [512]
  float* out = (float*)d_out;               // [64*512] out, then [64*768] z

  char* ws = (char*)d_ws;
  unsigned short* Lnb = (unsigned short*)ws;            // [0, 768K)
  float* em       = (float*)(ws + 786432);              // [768K, 896K)
  float* inv_norm = (float*)(ws + 917504);              // [896K, 1M)
  unsigned short* Vb = (unsigned short*)(ws + 1048576); // [1M, 1M+48M)
  const size_t vb_bytes = (size_t)BB * SS * DD * 2;     // 48 MB

  const size_t need16 = 1048576 + vb_bytes + (size_t)16 * BB * DD * 4;
  const bool big = ws_size >= need16;

  k_label_norm<<<CC, 256, 0, stream>>>(L, Lnb);
  if (big) {
    const int nsc = 16, spc = SS / nsc;
    float* zpart = (float*)(ws + 1048576 + vb_bytes);
    k_vprep<<<BB * SS / 4, 256, 0, stream>>>(V, Vb, inv_norm);
    k_sims_hs<<<256, 512, 0, stream>>>(Vb, inv_norm, Lnb, em);
    k_zpart_bf<<<BB * nsc, 192, 0, stream>>>(Vb, em, zpart, spc, nsc);
    k_final<<<2 * BB, 256, 0, stream>>>(zpart, em, fw, fb, out, out + BB * CC, nsc);
  } else {
    const int nsc = 8, spc = SS / nsc;
    float* zpart = (float*)(ws + 1048576);
    k_sims16<<<512, 256, 0, stream>>>(V, Lnb, em);
    k_zpart_f32<<<BB * nsc, 192, 0, stream>>>(V, em, zpart, spc, nsc);
    k_final<<<2 * BB, 256, 0, stream>>>(zpart, em, fw, fb, out, out + BB * CC, nsc);
  }
}